// Round 2
// baseline (496.584 us; speedup 1.0000x reference)
//
#include <hip/hip_runtime.h>
#include <cmath>

// Problem constants (from reference)
#define N_INPUTS 2048
#define UNITS    2048
#define L_LAYERS 8
#define FANIN    4096
#define TOTAL    18432           // N_INPUTS + L*UNITS

// Decomposition
#define NTHREADS 256
#define RK       16              // rows (k) per partial block
#define KC       (FANIN / RK)    // 256 k-chunks
#define JTILE    1024            // columns per partial block (256 thr * 4)
#define P_BLOCKS (2 * KC)        // 512 blocks: (j-half, k-chunk)

// ---------------------------------------------------------------------------
// init: outputs[0:2048] = x, outputs[2048:TOTAL] = 0   (ws poisoned each call)
// ---------------------------------------------------------------------------
__global__ __launch_bounds__(NTHREADS) void init_kernel(
    const float* __restrict__ x, float* __restrict__ outputs)
{
    int gtid = blockIdx.x * NTHREADS + threadIdx.x;
    if (gtid < TOTAL)
        outputs[gtid] = (gtid < N_INPUTS) ? x[gtid] : 0.0f;
}

// ---------------------------------------------------------------------------
// partial matvec for one layer: block = (j-half, 16-row k-chunk)
// partials[kc][j] = sum_{k in chunk} g[k] * W[layer][k][j]
// ---------------------------------------------------------------------------
__global__ __launch_bounds__(NTHREADS) void p_kernel(
    int layer,
    const int*   __restrict__ node_inds,
    const float* __restrict__ Ws,
    const float* __restrict__ outputs,
    float*       __restrict__ partials)
{
    const int b = blockIdx.x;
    const int t = threadIdx.x;
    const int jhalf = b & 1;
    const int kc    = b >> 1;

    __shared__ float gsh[RK];
    if (t < RK) {
        int idx = node_inds[layer * FANIN + kc * RK + t];
        gsh[t] = outputs[idx];          // un-filled slots are zero => correct
    }
    __syncthreads();

    const int jbase = jhalf * JTILE + t * 4;
    const float4* W4 = (const float4*)(
        Ws + ((size_t)layer * FANIN + (size_t)kc * RK) * UNITS + jbase);

    float4 a; a.x = 0.f; a.y = 0.f; a.z = 0.f; a.w = 0.f;
    #pragma unroll
    for (int k = 0; k < RK; ++k) {
        float  g = gsh[k];
        float4 w = W4[(size_t)k * (UNITS / 4)];   // row stride = 2048 floats
        a.x += g * w.x; a.y += g * w.y; a.z += g * w.z; a.w += g * w.w;
    }
    *(float4*)(partials + (size_t)kc * UNITS + jbase) = a;
}

// ---------------------------------------------------------------------------
// finalize one layer: column sum over KC partials + bias + tanh, scatter
// ---------------------------------------------------------------------------
__global__ __launch_bounds__(NTHREADS) void f_kernel(
    int layer,
    const float* __restrict__ partials,
    const float* __restrict__ bs,
    float*       __restrict__ outputs,
    float*       __restrict__ out)
{
    int col = blockIdx.x * NTHREADS + threadIdx.x;   // 8 blocks -> 2048 cols
    float s = 0.f;
    #pragma unroll 8
    for (int m = 0; m < KC; ++m)
        s += partials[(size_t)m * UNITS + col];
    float y = tanhf(s + bs[layer * UNITS + col]);
    if (layer == L_LAYERS - 1) out[col] = y;                 // final x_8
    else outputs[(layer + 1) * UNITS + col] = y;             // slot layer+1
}

// ---------------------------------------------------------------------------
extern "C" void kernel_launch(void* const* d_in, const int* in_sizes, int n_in,
                              void* d_out, int out_size, void* d_ws, size_t ws_size,
                              hipStream_t stream) {
    const float* x         = (const float*)d_in[0];
    const int*   node_inds = (const int*)  d_in[1];
    const float* Ws        = (const float*)d_in[2];
    const float* bs        = (const float*)d_in[3];
    float*       out       = (float*)d_out;
    float*       ws        = (float*)d_ws;

    float* outputs  = ws;            // TOTAL floats
    float* partials = ws + TOTAL;    // KC * UNITS floats (2 MiB)

    init_kernel<<<(TOTAL + NTHREADS - 1) / NTHREADS, NTHREADS, 0, stream>>>(
        x, outputs);

    for (int i = 0; i < L_LAYERS; ++i) {
        p_kernel<<<P_BLOCKS, NTHREADS, 0, stream>>>(
            i, node_inds, Ws, outputs, partials);
        f_kernel<<<UNITS / NTHREADS, NTHREADS, 0, stream>>>(
            i, partials, bs, outputs, out);
    }
}

// Round 4
// 416.888 us; speedup vs baseline: 1.1912x; 1.1912x over previous
//
#include <hip/hip_runtime.h>
#include <cmath>

// Problem constants (from reference)
#define N_INPUTS 2048
#define UNITS    2048
#define L_LAYERS 8
#define FANIN    4096
#define TOTAL    18432           // N_INPUTS + L*UNITS

// Decomposition
#define NTHREADS 256
#define RK       16              // rows (k) per partial block
#define KC       (FANIN / RK)    // 256 k-chunks (partial rows)
#define JTILE    1024            // columns per partial block (256 thr * 4)
#define P_BLOCKS (2 * KC)        // 512 blocks: (j-half, k-chunk)

// Wave-parallel reduction of one partials column (KC=256 rows).
// All 64 lanes of the calling wave must participate. Returns sum in all lanes.
__device__ __forceinline__ float col_reduce(const float* __restrict__ P, int col)
{
    int lane = threadIdx.x & 63;
    float s = 0.f;
    #pragma unroll
    for (int m = 0; m < KC / 64; ++m)
        s += P[(size_t)(lane + m * 64) * UNITS + col];
    #pragma unroll
    for (int off = 32; off; off >>= 1)
        s += __shfl_down(s, off, 64);
    return __shfl(s, 0, 64);
}

// ---------------------------------------------------------------------------
// Fused per-layer kernel. Dispatch `layer` does, in order:
//   1. finalize slot `layer` of the state vector (4 owned columns per block)
//      from Pprev (layer-1 partials) — or copy x into slot 0 when layer==0.
//   2. compute this block's 16 gather activations:
//        idx <  layer*2048          -> outputs[idx]  (materialized earlier)
//        idx in slot `layer`        -> recompute locally from Pprev
//        idx >= (layer+1)*2048      -> 0
//   3. stream its 16x1024 weight tile, write partial sums to Pcur.
// Cross-block visibility is provided solely by dispatch boundaries.
// ---------------------------------------------------------------------------
__global__ __launch_bounds__(NTHREADS) void layer_kernel(
    int layer,
    const float* __restrict__ x,
    const int*   __restrict__ node_inds,
    const float* __restrict__ Ws,
    const float* __restrict__ bs,
    float*       __restrict__ outputs,
    const float* __restrict__ Pprev,
    float*       __restrict__ Pcur)
{
    const int b    = blockIdx.x;
    const int t    = threadIdx.x;
    const int wv   = t >> 6;          // wave 0..3
    const int lane = t & 63;
    const int jhalf = b & 1;
    const int kc    = b >> 1;

    __shared__ float gsh[RK];

    // ---- 1. finalize owned column of slot `layer` (one column per wave)
    {
        int col = b * 4 + wv;         // 512 blocks * 4 = 2048 columns
        if (layer == 0) {
            if (lane == 0) outputs[col] = x[col];
        } else {
            float s = col_reduce(Pprev, col);
            float y = tanhf(s + bs[(layer - 1) * UNITS + col]);
            if (lane == 0) outputs[(size_t)layer * UNITS + col] = y;
        }
    }

    // ---- 2. gather activations (4 indices per wave; idx is wave-uniform)
    #pragma unroll
    for (int j = 0; j < 4; ++j) {
        int q   = wv * 4 + j;
        int idx = node_inds[layer * FANIN + kc * RK + q];
        float g;
        if (layer == 0) {
            g = (idx < N_INPUTS) ? x[idx] : 0.f;
        } else if (idx < layer * UNITS) {
            g = outputs[idx];
        } else if (idx < (layer + 1) * UNITS) {
            int col = idx - layer * UNITS;
            float s = col_reduce(Pprev, col);
            g = tanhf(s + bs[(layer - 1) * UNITS + col]);
        } else {
            g = 0.f;
        }
        if (lane == 0) gsh[q] = g;
    }
    __syncthreads();

    // ---- 3. partial matvec: stream 16 rows x 1024 cols of W
    const int jbase = jhalf * JTILE + t * 4;
    const float4* W4 = (const float4*)(
        Ws + ((size_t)layer * FANIN + (size_t)kc * RK) * UNITS + jbase);

    float4 a; a.x = 0.f; a.y = 0.f; a.z = 0.f; a.w = 0.f;
    #pragma unroll
    for (int k = 0; k < RK; ++k) {
        float  g = gsh[k];
        float4 w = W4[(size_t)k * (UNITS / 4)];   // row stride = 2048 floats
        a.x += g * w.x; a.y += g * w.y; a.z += g * w.z; a.w += g * w.w;
    }
    *(float4*)(Pcur + (size_t)kc * UNITS + jbase) = a;
}

// ---------------------------------------------------------------------------
// Tail: out[col] = tanh(sum(P7[:,col]) + bs[7][col])
// 512 blocks x 4 waves -> one column per wave, covers all 2048 columns.
// ---------------------------------------------------------------------------
__global__ __launch_bounds__(NTHREADS) void tail_kernel(
    const float* __restrict__ Pprev,
    const float* __restrict__ bs,
    float*       __restrict__ out)
{
    int wv   = threadIdx.x >> 6;
    int lane = threadIdx.x & 63;
    int col  = blockIdx.x * 4 + wv;
    float s = col_reduce(Pprev, col);
    float y = tanhf(s + bs[(L_LAYERS - 1) * UNITS + col]);
    if (lane == 0) out[col] = y;
}

// ---------------------------------------------------------------------------
extern "C" void kernel_launch(void* const* d_in, const int* in_sizes, int n_in,
                              void* d_out, int out_size, void* d_ws, size_t ws_size,
                              hipStream_t stream) {
    const float* x         = (const float*)d_in[0];
    const int*   node_inds = (const int*)  d_in[1];
    const float* Ws        = (const float*)d_in[2];
    const float* bs        = (const float*)d_in[3];
    float*       out       = (float*)d_out;
    float*       ws        = (float*)d_ws;

    float* outputs = ws;                        // TOTAL floats
    float* P0      = ws + TOTAL;                // KC*UNITS floats (2 MiB)
    float* P1      = P0 + (size_t)KC * UNITS;   // KC*UNITS floats (2 MiB)

    float* pbuf[2] = { P0, P1 };

    for (int i = 0; i < L_LAYERS; ++i) {
        layer_kernel<<<P_BLOCKS, NTHREADS, 0, stream>>>(
            i, x, node_inds, Ws, bs, outputs,
            pbuf[(i + 1) & 1],   // Pprev (unused when i==0)
            pbuf[i & 1]);        // Pcur
    }
    tail_kernel<<<UNITS / 4, NTHREADS, 0, stream>>>(
        pbuf[(L_LAYERS - 1) & 1], bs, out);
}